// Round 4
// baseline (1984.074 us; speedup 1.0000x reference)
//
#include <hip/hip_runtime.h>

// ---------------------------------------------------------------------------
// FutureCameraHead on MI355X (gfx950) — 5 dispatches total.
// trunk_k : both ResConvBlocks (6 Linears) fused. 64-row x 512-col LDS tile,
//           acc[2][2] per wave (64 AGPR -> 4 waves/SIMD), barrier-free K-loop
//           with depth-2 W prefetch, coalesced residual epilogues via LDS.
// pool_k  : mean over patch grid (atomic partials).
// tail_k  : whole post-pool MLP chain + fp64 Jacobi SVD, per-row fused.
// ---------------------------------------------------------------------------

typedef unsigned short u16;
typedef __attribute__((ext_vector_type(8))) short short8;    // 8 x bf16
typedef __attribute__((ext_vector_type(16))) float f32x16;   // 32x32 MFMA acc

constexpr int  DDIM   = 512;
constexpr long R_ROWS = 96L * 1369L;   // 131424 (BN * hw)
constexpr long R_PAD  = 2054L * 64L;   // 131456 buffer rows

__device__ __forceinline__ u16 f2b(float f) {  // fp32 -> bf16 RNE
  union { float f; unsigned u; } x; x.f = f;
  unsigned r = (x.u + 0x7FFFu + ((x.u >> 16) & 1u)) >> 16;
  return (u16)r;
}
__device__ __forceinline__ float b2f(u16 b) {
  union { unsigned u; float f; } x; x.u = ((unsigned)b) << 16;
  return x.f;
}

// --- W_res [6][K=512][N=512] fp32 -> fragment-linear packed bf16 ------------
// Wp flat = (k8*512 + n)*8 + j  holds W[k8*8 + j][n]   (k8 = k-octet)
__global__ void pack_w_k(const float* __restrict__ W, u16* __restrict__ Wp) {
  int tid = blockIdx.x * 256 + threadIdx.x;
  if (tid >= 6 * 262144) return;
  int g  = tid >> 18, t2 = tid & 262143;
  int k8 = t2 >> 12, t3 = t2 & 4095;
  int n  = t3 >> 3,  j  = t3 & 7;
  int k  = k8 * 8 + j;
  Wp[tid] = f2b(W[(long)g * 262144 + (long)k * 512 + n]);
}

// --- trunk: 6 fused layers, residual after layer 3 and 6 --------------------
__global__ __launch_bounds__(512, 3)
void trunk_k(const float* __restrict__ feat, u16* __restrict__ A,
             const u16* __restrict__ Wp, const float* __restrict__ bres) {
  __shared__ u16 Yb[64 * 512];   // 64 KB, chunk(r,k8) at r*64 + (k8^r)
  const int tid  = threadIdx.x;
  const int lane = tid & 63;
  const int wv   = tid >> 6;     // 8 waves, 64 out-cols each
  const int l31  = lane & 31;
  const int q    = lane >> 5;
  const int colBase = wv * 64;
  const long rowBase = (long)blockIdx.x * 64;

  // ---- stage: fp32 feat -> bf16 swizzled LDS + write-through res1 -> A ----
#pragma unroll
  for (int i = 0; i < 16; ++i) {
    int f4 = i * 512 + tid;            // 8192 float4 chunks (64 rows x 128)
    int r = f4 >> 7, c4 = f4 & 127;
    int k = c4 * 4;
    long grow = rowBase + r;
    float4 v = {0.f, 0.f, 0.f, 0.f};
    if (grow < R_ROWS) v = *(const float4*)(feat + grow * DDIM + k);
    ushort4 pk;
    pk.x = f2b(v.x); pk.y = f2b(v.y); pk.z = f2b(v.z); pk.w = f2b(v.w);
    int k8 = c4 >> 1, half = c4 & 1;
    *(ushort4*)&Yb[(r * 64 + (k8 ^ r)) * 8 + half * 4] = pk;
    *(ushort4*)(A + grow * DDIM + k) = pk;   // res1 (pad rows get zeros)
  }
  __syncthreads();

  for (int l = 0; l < 6; ++l) {
    const u16* wl = Wp + (long)l * 262144;
    const float* bias = bres + l * 512;

    f32x16 acc[2][2];
#pragma unroll
    for (int mi = 0; mi < 2; ++mi)
#pragma unroll
      for (int nb = 0; nb < 2; ++nb)
#pragma unroll
        for (int e = 0; e < 16; ++e) acc[mi][nb][e] = 0.f;

    // lambdas: W frag (2 mi) and X frag (2 nb) loads for k-step ks
    auto loadW = [&](short8* w, int ks) {
      const u16* wk = wl + ((long)(ks * 2 + q) * 512 + colBase + l31) * 8;
      w[0] = *(const short8*)wk;
      w[1] = *(const short8*)(wk + 32 * 8);
    };
    auto loadX = [&](short8* x, int ks) {
      int k8 = ks * 2 + q;
#pragma unroll
      for (int nb = 0; nb < 2; ++nb) {
        int r = nb * 32 + l31;
        x[nb] = *(const short8*)&Yb[(r * 64 + (k8 ^ r)) * 8];
      }
    };

    short8 wA[2], wB[2], xA[2];
    loadW(wA, 0); loadW(wB, 1); loadX(xA, 0);
#pragma unroll
    for (int ks = 0; ks < 32; ++ks) {
      short8 wC[2], xN[2];
      loadW(wC, ks < 30 ? ks + 2 : ks);    // depth-2 W prefetch (clamped)
      loadX(xN, ks < 31 ? ks + 1 : ks);    // depth-1 X prefetch
#pragma unroll
      for (int mi = 0; mi < 2; ++mi)
#pragma unroll
        for (int nb = 0; nb < 2; ++nb)
          acc[mi][nb] = __builtin_amdgcn_mfma_f32_32x32x16_bf16(
              wA[mi], xA[nb], acc[mi][nb], 0, 0, 0);
      wA[0] = wB[0]; wA[1] = wB[1];
      wB[0] = wC[0]; wB[1] = wC[1];
      xA[0] = xN[0]; xA[1] = xN[1];
    }
    __syncthreads();   // all Yb reads done before epilogue overwrites

    // ---- epilogue: relu(acc+bias) -> Yb (bf16, swizzled) ----
    // C/D: n(row) = lane&31 (+nb*32), m(col) = (reg&3) + 8*(reg>>2) + 4*q
#pragma unroll
    for (int mi = 0; mi < 2; ++mi) {
#pragma unroll
      for (int j2 = 0; j2 < 4; ++j2) {
        int n0 = colBase + mi * 32 + 4 * q + 8 * j2;
        float4 bv = *(const float4*)(bias + n0);
#pragma unroll
        for (int nb = 0; nb < 2; ++nb) {
          int r = nb * 32 + l31;
          ushort4 pk;
          pk.x = f2b(fmaxf(acc[mi][nb][4 * j2 + 0] + bv.x, 0.f));
          pk.y = f2b(fmaxf(acc[mi][nb][4 * j2 + 1] + bv.y, 0.f));
          pk.z = f2b(fmaxf(acc[mi][nb][4 * j2 + 2] + bv.z, 0.f));
          pk.w = f2b(fmaxf(acc[mi][nb][4 * j2 + 3] + bv.w, 0.f));
          *(ushort4*)&Yb[(r * 64 + ((n0 >> 3) ^ r)) * 8 + (n0 & 7)] = pk;
        }
      }
    }
    __syncthreads();

    if (l == 2 || l == 5) {
      // ---- residual pass (fully coalesced 16B lanes): A += Yb ----
#pragma unroll
      for (int i = 0; i < 8; ++i) {
        int L = i * 512 + tid;           // 4096 chunks of 16 B
        int r = L >> 6, cS = L & 63, c = cS ^ r;
        long off = (rowBase + r) * DDIM + c * 8;
        short8 y = *(const short8*)&Yb[L * 8];
        short8 rs = *(const short8*)(A + off);
        short8 o;
#pragma unroll
        for (int e = 0; e < 8; ++e)
          o[e] = (short)f2b(b2f((u16)y[e]) + b2f((u16)rs[e]));
        *(short8*)(A + off) = o;          // res for next block / final out
        if (l == 2) *(short8*)&Yb[L * 8] = o;  // feed layer 4
      }
      __syncthreads();
    }
  }
}

// --- pooling: pooled[bn][d] = mean_p A[bn*1369+p][d] ------------------------
__global__ void zero_k(float* p, int n) {
  int i = blockIdx.x * 256 + threadIdx.x;
  if (i < n) p[i] = 0.f;
}

__global__ void pool_k(const u16* __restrict__ A, float* __restrict__ pooled) {
  int bn = blockIdx.x, ch = blockIdx.y, d = threadIdx.x;  // block 512
  int p0 = ch * 172, p1 = p0 + 172;
  if (p1 > 1369) p1 = 1369;
  float s = 0.f;
  long base = ((long)bn * 1369 + p0) * DDIM + d;
#pragma unroll 4
  for (int p = p0; p < p1; ++p) { s += b2f(A[base]); base += DDIM; }
  atomicAdd(&pooled[bn * DDIM + d], s * (1.0f / 1369.0f));
}

// --- fp64 Jacobi SVD orthogonalize + 4x4 pose assemble ----------------------
__device__ void svd_pose(const float* pin, float* o) {
  double t3[3] = {pin[0], pin[1], pin[2]};
  double m[3][3];
  for (int i = 0; i < 3; ++i)
    for (int j = 0; j < 3; ++j) m[i][j] = (double)pin[3 + i * 3 + j];
  for (int i = 0; i < 3; ++i) {
    double nn = sqrt(m[i][0] * m[i][0] + m[i][1] * m[i][1] + m[i][2] * m[i][2]);
    if (nn < 1e-12) nn = 1e-12;
    m[i][0] /= nn; m[i][1] /= nn; m[i][2] /= nn;
  }
  double Km[3][3];
  for (int a = 0; a < 3; ++a)
    for (int b = 0; b < 3; ++b) {
      double s = 0;
      for (int i = 0; i < 3; ++i) s += m[i][a] * m[i][b];
      Km[a][b] = s;
    }
  double V[3][3] = {{1, 0, 0}, {0, 1, 0}, {0, 0, 1}};
  const int PQ[3][2] = {{0, 1}, {0, 2}, {1, 2}};
  for (int sweep = 0; sweep < 20; ++sweep) {
    for (int e = 0; e < 3; ++e) {
      int p = PQ[e][0], qq = PQ[e][1];
      double apq = Km[p][qq];
      if (apq == 0.0) continue;
      double tau = (Km[qq][qq] - Km[p][p]) / (2.0 * apq);
      double tt = (tau >= 0.0 ? 1.0 : -1.0) / (fabs(tau) + sqrt(1.0 + tau * tau));
      double cc = 1.0 / sqrt(1.0 + tt * tt), ss = tt * cc;
      for (int k = 0; k < 3; ++k) { double a1 = Km[p][k], a2 = Km[qq][k]; Km[p][k] = cc * a1 - ss * a2; Km[qq][k] = ss * a1 + cc * a2; }
      for (int k = 0; k < 3; ++k) { double a1 = Km[k][p], a2 = Km[k][qq]; Km[k][p] = cc * a1 - ss * a2; Km[k][qq] = ss * a1 + cc * a2; }
      for (int k = 0; k < 3; ++k) { double a1 = V[k][p], a2 = V[k][qq]; V[k][p] = cc * a1 - ss * a2; V[k][qq] = ss * a1 + cc * a2; }
    }
  }
  double lam[3] = {Km[0][0], Km[1][1], Km[2][2]};
  int o0 = 0, o1 = 1, o2 = 2; double detV = 1.0;
  if (lam[o0] < lam[o1]) { int t = o0; o0 = o1; o1 = t; detV = -detV; }
  if (lam[o1] < lam[o2]) { int t = o1; o1 = o2; o2 = t; detV = -detV; }
  if (lam[o0] < lam[o1]) { int t = o0; o0 = o1; o1 = t; detV = -detV; }
  double v0[3] = {V[0][o0], V[1][o0], V[2][o0]};
  double v1[3] = {V[0][o1], V[1][o1], V[2][o1]};
  double v2[3] = {V[0][o2], V[1][o2], V[2][o2]};
  double u0[3], u1[3];
  for (int i = 0; i < 3; ++i) u0[i] = m[i][0] * v0[0] + m[i][1] * v0[1] + m[i][2] * v0[2];
  double n0 = sqrt(u0[0] * u0[0] + u0[1] * u0[1] + u0[2] * u0[2]); if (n0 < 1e-30) n0 = 1e-30;
  for (int i = 0; i < 3; ++i) u0[i] /= n0;
  for (int i = 0; i < 3; ++i) u1[i] = m[i][0] * v1[0] + m[i][1] * v1[1] + m[i][2] * v1[2];
  double d01 = u0[0] * u1[0] + u0[1] * u1[1] + u0[2] * u1[2];
  for (int i = 0; i < 3; ++i) u1[i] -= d01 * u0[i];
  double n1 = sqrt(u1[0] * u1[0] + u1[1] * u1[1] + u1[2] * u1[2]); if (n1 < 1e-30) n1 = 1e-30;
  for (int i = 0; i < 3; ++i) u1[i] /= n1;
  double u2[3] = {u0[1] * u1[2] - u0[2] * u1[1],
                  u0[2] * u1[0] - u0[0] * u1[2],
                  u0[0] * u1[1] - u0[1] * u1[0]};
  for (int i = 0; i < 3; ++i) {
    for (int j = 0; j < 3; ++j)
      o[i * 4 + j] = (float)(u0[i] * v0[j] + u1[i] * v1[j] + detV * u2[i] * v2[j]);
    o[i * 4 + 3] = (float)t3[i];
  }
  o[12] = 0.f; o[13] = 0.f; o[14] = 0.f; o[15] = 1.f;
}

// --- tail: whole post-pool network, 8 rows per block ------------------------
// blocks 0..11: cur rows (pooled -> cur1 -> cur2 -> m1 -> m2 -> pose)
// blocks 12..23: fut rows (gctx -> tp1 -> tp2[m0] -> fut1 -> fut2 -> m1 -> m2 -> pose)
__global__ void tail_k(const float* __restrict__ pooled,
                       const float* Wc1, const float* bc1, const float* Wc2, const float* bc2,
                       const float* Wt1, const float* bt1, const float* Wt2, const float* bt2,
                       const float* Wf1, const float* bf1, const float* Wf2, const float* bf2,
                       const float* Wm1, const float* bm1, const float* Wm2, const float* bm2,
                       const float* Wt, const float* bt, const float* Wr, const float* br,
                       float* __restrict__ out) {
  __shared__ float bufA[8][512];
  __shared__ float bufB[8][512];
  __shared__ float pose_in[8][12];
  const int blk = blockIdx.x;     // 24
  const int tid = threadIdx.x;    // 512
  const bool isFut = blk >= 12;
  int m0 = 0, b0 = 0;
  if (!isFut) {
    int r0 = blk * 8;
#pragma unroll
    for (int r = 0; r < 8; ++r) bufA[r][tid] = pooled[(r0 + r) * 512 + tid];
  } else {
    int f = blk - 12; m0 = f >> 2; b0 = (f & 3) * 8;
#pragma unroll
    for (int r = 0; r < 8; ++r) {
      int b = b0 + r;
      bufA[r][tid] = (pooled[(b * 3 + 0) * 512 + tid] +
                      pooled[(b * 3 + 1) * 512 + tid] +
                      pooled[(b * 3 + 2) * 512 + tid]) * (1.0f / 3.0f);
    }
  }
  __syncthreads();

  auto layer = [&](float (*in)[512], float (*ob)[512], const float* W, int ldw,
                   int coff, const float* b, bool relu) {
    int n = tid;
    float acc[8];
#pragma unroll
    for (int r = 0; r < 8; ++r) acc[r] = b[coff + n];
    for (int k = 0; k < 512; k += 4) {
      float w0 = W[(long)(k + 0) * ldw + coff + n];
      float w1 = W[(long)(k + 1) * ldw + coff + n];
      float w2 = W[(long)(k + 2) * ldw + coff + n];
      float w3 = W[(long)(k + 3) * ldw + coff + n];
#pragma unroll
      for (int r = 0; r < 8; ++r) {
        float4 x = *(const float4*)&in[r][k];
        acc[r] = fmaf(x.x, w0, acc[r]);
        acc[r] = fmaf(x.y, w1, acc[r]);
        acc[r] = fmaf(x.z, w2, acc[r]);
        acc[r] = fmaf(x.w, w3, acc[r]);
      }
    }
#pragma unroll
    for (int r = 0; r < 8; ++r) ob[r][n] = relu ? fmaxf(acc[r], 0.f) : acc[r];
    __syncthreads();
  };

  if (!isFut) {
    layer(bufA, bufB, Wc1, 512, 0, bc1, true);
    layer(bufB, bufA, Wc2, 512, 0, bc2, false);
    layer(bufA, bufB, Wm1, 512, 0, bm1, true);
    layer(bufB, bufA, Wm2, 512, 0, bm2, true);
  } else {
    layer(bufA, bufB, Wt1, 512, 0, bt1, true);
    layer(bufB, bufA, Wt2, 1536, m0 * 512, bt2, false);
    layer(bufA, bufB, Wf1, 512, 0, bf1, true);
    layer(bufB, bufA, Wf2, 512, 0, bf2, false);
    layer(bufA, bufB, Wm1, 512, 0, bm1, true);
    layer(bufB, bufA, Wm2, 512, 0, bm2, true);
  }
  // h is in bufA. 12 pose dots per row, then SIMT fp64 SVD (8 rows in a wave).
  int r = tid >> 6, c = tid & 63;
  if (c < 12) {
    float acc = (c < 3) ? bt[c] : br[c - 3];
    for (int k = 0; k < 512; ++k) {
      float w = (c < 3) ? Wt[k * 3 + c] : Wr[k * 9 + (c - 3)];
      acc = fmaf(bufA[r][k], w, acc);
    }
    pose_in[r][c] = acc;
  }
  __syncthreads();
  if (tid < 8) {
    int grow = isFut ? (96 + (b0 + tid) * 3 + m0) : (blk * 8 + tid);
    svd_pose(&pose_in[tid][0], out + (long)grow * 16);
  }
}

// ---------------------------------------------------------------------------
extern "C" void kernel_launch(void* const* d_in, const int* in_sizes, int n_in,
                              void* d_out, int out_size, void* d_ws, size_t ws_size,
                              hipStream_t stream) {
  (void)in_sizes; (void)n_in; (void)out_size; (void)ws_size;
  const float* feat   = (const float*)d_in[0];
  const float* W_res  = (const float*)d_in[5];
  const float* b_res  = (const float*)d_in[6];
  const float* W_cur1 = (const float*)d_in[7];
  const float* b_cur1 = (const float*)d_in[8];
  const float* W_cur2 = (const float*)d_in[9];
  const float* b_cur2 = (const float*)d_in[10];
  const float* W_tp1  = (const float*)d_in[11];
  const float* b_tp1  = (const float*)d_in[12];
  const float* W_tp2  = (const float*)d_in[13];
  const float* b_tp2  = (const float*)d_in[14];
  const float* W_fut1 = (const float*)d_in[15];
  const float* b_fut1 = (const float*)d_in[16];
  const float* W_fut2 = (const float*)d_in[17];
  const float* b_fut2 = (const float*)d_in[18];
  const float* W_m1   = (const float*)d_in[19];
  const float* b_m1   = (const float*)d_in[20];
  const float* W_m2   = (const float*)d_in[21];
  const float* b_m2   = (const float*)d_in[22];
  const float* W_t    = (const float*)d_in[23];
  const float* b_t    = (const float*)d_in[24];
  const float* W_r    = (const float*)d_in[25];
  const float* b_r    = (const float*)d_in[26];

  char* ws = (char*)d_ws;
  const size_t SZ_BIG = (size_t)R_PAD * DDIM * 2;  // 134,610,944 B
  u16* A  = (u16*)(ws);                     // bf16 activations / residuals
  u16* Wp = (u16*)(ws + SZ_BIG);            // packed trunk weights (3 MB)
  float* pooled = (float*)(ws + SZ_BIG + (size_t)6 * 262144 * 2);  // [96][512]
  float* outp   = (float*)d_out;

  pack_w_k<<<6144, 256, 0, stream>>>(W_res, Wp);
  trunk_k<<<2054, 512, 0, stream>>>(feat, A, Wp, b_res);

  zero_k<<<(96 * 512 + 255) / 256, 256, 0, stream>>>(pooled, 96 * 512);
  pool_k<<<dim3(96, 8), 512, 0, stream>>>(A, pooled);

  tail_k<<<24, 512, 0, stream>>>(pooled,
      W_cur1, b_cur1, W_cur2, b_cur2, W_tp1, b_tp1, W_tp2, b_tp2,
      W_fut1, b_fut1, W_fut2, b_fut2, W_m1, b_m1, W_m2, b_m2,
      W_t, b_t, W_r, b_r, outp);
}